// Round 3
// baseline (154.597 us; speedup 1.0000x reference)
//
#include <hip/hip_runtime.h>
#include <hip/hip_bf16.h>

#define B_SZ   4
#define DEC_SZ 128
#define ENC_SZ 512
#define H_SZ   768
#define OUT_N  (B_SZ * DEC_SZ * ENC_SZ)

typedef __attribute__((ext_vector_type(8))) short s8v;   // 8 bf16 (4 VGPRs)
typedef __attribute__((ext_vector_type(4))) float fvec4; // MFMA accumulator

// fp32 -> bf16, round-to-nearest-even
__device__ inline unsigned short f2bf(float x) {
  union { float f; unsigned u; } v; v.f = x;
  unsigned r = v.u + 0x7FFF + ((v.u >> 16) & 1);
  return (unsigned short)(r >> 16);
}

// ---------------------------------------------------------------------------
// Prep: transpose W (768x768 fp32, (k,n)) -> WT bf16 (n,k). z selects W1/W2.
// ---------------------------------------------------------------------------
__global__ __launch_bounds__(256) void transpose_w(const float* __restrict__ W1,
                                                   const float* __restrict__ W2,
                                                   unsigned short* __restrict__ T1,
                                                   unsigned short* __restrict__ T2) {
  const float* W = blockIdx.z ? W2 : W1;
  unsigned short* T = blockIdx.z ? T2 : T1;
  __shared__ float tile[64][65];
  int c0 = blockIdx.x * 64;
  int r0 = blockIdx.y * 64;
  int tx = threadIdx.x & 63, ty = threadIdx.x >> 6;
#pragma unroll
  for (int i = 0; i < 16; ++i) {
    int r = ty + i * 4;
    tile[r][tx] = W[(size_t)(r0 + r) * H_SZ + c0 + tx];
  }
  __syncthreads();
#pragma unroll
  for (int i = 0; i < 16; ++i) {
    int c = ty + i * 4;
    T[(size_t)(c0 + c) * H_SZ + r0 + tx] = f2bf(tile[tx][c]);
  }
}

// Prep: fp32 -> bf16 for enc (z=0) and dec (z=1)
__global__ __launch_bounds__(256) void cast_bf16(const float* __restrict__ enc,
                                                 const float* __restrict__ dec,
                                                 unsigned short* __restrict__ encB,
                                                 unsigned short* __restrict__ decB) {
  const float* x = blockIdx.z ? dec : enc;
  unsigned short* y = blockIdx.z ? decB : encB;
  int n4 = blockIdx.z ? (B_SZ * DEC_SZ * H_SZ / 4) : (B_SZ * ENC_SZ * H_SZ / 4);
  int i = blockIdx.x * 256 + threadIdx.x;
  if (i >= n4) return;
  float4 v = ((const float4*)x)[i];
  ushort4 o;
  o.x = f2bf(v.x); o.y = f2bf(v.y); o.z = f2bf(v.z); o.w = f2bf(v.w);
  ((ushort4*)y)[i] = o;
}

// ---------------------------------------------------------------------------
// MFMA NT GEMM + exp2 epilogue, register-prefetch double-buffered.
// C[m][n] = exp2(C2 * sum_k A[m][k]*B[n][k]);  A,B bf16 with k-contiguous rows
// of length H_SZ. Tile TM x 64, BK=32. 4 waves; wave w owns rows
// [w*TM/4, (w+1)*TM/4) x all 64 n.
// ---------------------------------------------------------------------------
template <int TM>
__global__ __launch_bounds__(256) void gemm_nt_exp(const unsigned short* __restrict__ A,
                                                   const unsigned short* __restrict__ Bm,
                                                   float* __restrict__ C, int ldc) {
  const int m0 = blockIdx.x * TM;
  const int n0 = blockIdx.y * 64;

  __shared__ unsigned short As[TM][40];  // pad 40: 80 B rows
  __shared__ unsigned short Bs[64][40];

  const int tid  = threadIdx.x;
  const int wave = tid >> 6;
  const int lane = tid & 63;
  const int l16  = lane & 15;
  const int quad = lane >> 4;
  const int MI   = TM / 64;            // af count (2 for TM=128, 1 for TM=64)
  const int wm   = wave * (TM / 4);

  // staging decomposition: segments of 8 bf16
  const int ASEG = TM * 4 / 256;       // per-thread A segments
  int ar[2], ak[2];
#pragma unroll
  for (int i = 0; i < ASEG; ++i) {
    int seg = tid + 256 * i;
    ar[i] = seg >> 2; ak[i] = (seg & 3) * 8;
  }
  const int br = tid >> 2, bk = (tid & 3) * 8;

  fvec4 acc[2][4];
#pragma unroll
  for (int i = 0; i < 2; ++i)
#pragma unroll
    for (int j = 0; j < 4; ++j) acc[i][j] = (fvec4)0.f;

  // prefetch tile 0
  s8v pa[2], pb;
#pragma unroll
  for (int i = 0; i < ASEG; ++i)
    pa[i] = *(const s8v*)(A + (size_t)(m0 + ar[i]) * H_SZ + ak[i]);
  pb = *(const s8v*)(Bm + (size_t)(n0 + br) * H_SZ + bk);

  for (int k0 = 0; k0 < H_SZ; k0 += 32) {
    __syncthreads();                      // previous tile's frag reads done
#pragma unroll
    for (int i = 0; i < ASEG; ++i) *(s8v*)&As[ar[i]][ak[i]] = pa[i];
    *(s8v*)&Bs[br][bk] = pb;
    __syncthreads();

    if (k0 + 32 < H_SZ) {                 // prefetch next tile into regs
#pragma unroll
      for (int i = 0; i < ASEG; ++i)
        pa[i] = *(const s8v*)(A + (size_t)(m0 + ar[i]) * H_SZ + k0 + 32 + ak[i]);
      pb = *(const s8v*)(Bm + (size_t)(n0 + br) * H_SZ + k0 + 32 + bk);
    }

    s8v af[2], bf[4];
#pragma unroll
    for (int i = 0; i < MI; ++i) af[i] = *(const s8v*)&As[wm + i * 16 + l16][quad * 8];
#pragma unroll
    for (int j = 0; j < 4; ++j) bf[j] = *(const s8v*)&Bs[j * 16 + l16][quad * 8];
#pragma unroll
    for (int i = 0; i < MI; ++i)
#pragma unroll
      for (int j = 0; j < 4; ++j)
        acc[i][j] = __builtin_amdgcn_mfma_f32_16x16x32_bf16(af[i], bf[j], acc[i][j], 0, 0, 0);
  }

  const float C2 = 2.885390082f;  // 2 * log2(e)
#pragma unroll
  for (int i = 0; i < MI; ++i) {
    int m = m0 + wm + i * 16 + quad * 4;  // C/D: row = quad*4 + reg, col = lane&15
#pragma unroll
    for (int j = 0; j < 4; ++j) {
      int n = n0 + j * 16 + l16;
#pragma unroll
      for (int r = 0; r < 4; ++r)
        C[(size_t)(m + r) * ldc + n] = __builtin_amdgcn_exp2f(acc[i][j][r] * C2);
    }
  }
}

// ---------------------------------------------------------------------------
// Fused score + mask + outputs.
// out0[b][d][e] = sumv - 2*sum_k vk/(1+pe[k][(b,e)]*pd[(b,d)][k]) + mask
// out1 = same without mask.
// Grid (ENC/64, DEC/8, B); block 128 (2 waves). lane = e within 64-strip;
// wave w owns d = d0 + w*4 .. +3, full k = 768.
// ---------------------------------------------------------------------------
__global__ __launch_bounds__(128) void score_out(const float* __restrict__ peT,
                                                 const float* __restrict__ pdm,
                                                 const float* __restrict__ vt,
                                                 const float* __restrict__ mask,
                                                 float* __restrict__ out) {
  const int tid  = threadIdx.x;
  const int wave = tid >> 6;
  const int lane = tid & 63;
  const int e    = blockIdx.x * 64 + lane;
  const int d0   = blockIdx.y * 8;
  const int b    = blockIdx.z;

  __shared__ float pd_s[H_SZ][8];   // [k][d], 24 KB; b128 at &pd_s[k][w*4]
  __shared__ float vts[H_SZ];

  {  // stage pd: thread = (dloc = tid>>4, l16 = tid&15)
    const int dloc = tid >> 4, l16 = tid & 15;
    const float* row = pdm + (size_t)(b * DEC_SZ + d0 + dloc) * H_SZ;
#pragma unroll
    for (int i = 0; i < 12; ++i) {
      int kb = (i * 16 + l16) * 4;
      float4 v = *(const float4*)(row + kb);
      pd_s[kb + 0][dloc] = v.x; pd_s[kb + 1][dloc] = v.y;
      pd_s[kb + 2][dloc] = v.z; pd_s[kb + 3][dloc] = v.w;
    }
#pragma unroll
    for (int i = 0; i < 6; ++i) vts[tid + 128 * i] = vt[tid + 128 * i];
  }
  __syncthreads();

  // sumv = sum(vt) via lane-strided + butterfly
  float sumv = 0.f;
#pragma unroll
  for (int j = 0; j < 12; ++j) sumv += vts[lane + 64 * j];
#pragma unroll
  for (int s = 1; s < 64; s <<= 1) sumv += __shfl_xor(sumv, s, 64);

  float t[4] = {0.f, 0.f, 0.f, 0.f};
  const float* pecol = peT + (size_t)b * ENC_SZ + e;  // column (b,e); row stride B*ENC

  float buf[8];
#pragma unroll
  for (int i = 0; i < 8; ++i) buf[i] = pecol[(size_t)i * (B_SZ * ENC_SZ)];

  for (int c = 0; c < H_SZ / 8; ++c) {
    float cur[8];
#pragma unroll
    for (int i = 0; i < 8; ++i) cur[i] = buf[i];
    if (c + 1 < H_SZ / 8) {
#pragma unroll
      for (int i = 0; i < 8; ++i)
        buf[i] = pecol[(size_t)(c * 8 + 8 + i) * (B_SZ * ENC_SZ)];
    }
#pragma unroll
    for (int i = 0; i < 8; ++i) {
      int k = c * 8 + i;
      float vk = vts[k];
      const float4 pd4 = *(const float4*)&pd_s[k][wave * 4];
      t[0] = fmaf(vk, __builtin_amdgcn_rcpf(fmaf(cur[i], pd4.x, 1.f)), t[0]);
      t[1] = fmaf(vk, __builtin_amdgcn_rcpf(fmaf(cur[i], pd4.y, 1.f)), t[1]);
      t[2] = fmaf(vk, __builtin_amdgcn_rcpf(fmaf(cur[i], pd4.z, 1.f)), t[2]);
      t[3] = fmaf(vk, __builtin_amdgcn_rcpf(fmaf(cur[i], pd4.w, 1.f)), t[3]);
    }
  }

#pragma unroll
  for (int dd = 0; dd < 4; ++dd) {
    int d = d0 + wave * 4 + dd;
    size_t idx = ((size_t)(b * DEC_SZ + d)) * ENC_SZ + e;
    float s = fmaf(-2.f, t[dd], sumv);
    out[idx] = s + mask[idx];
    out[OUT_N + idx] = s;
  }
}

extern "C" void kernel_launch(void* const* d_in, const int* in_sizes, int n_in,
                              void* d_out, int out_size, void* d_ws, size_t ws_size,
                              hipStream_t stream) {
  (void)in_sizes; (void)n_in; (void)out_size; (void)ws_size;
  const float* dec  = (const float*)d_in[0];  // (B, DEC, H)
  const float* enc  = (const float*)d_in[1];  // (B, ENC, H)
  const float* mask = (const float*)d_in[2];  // (B, DEC, ENC)
  const float* W1   = (const float*)d_in[3];  // (H, H) (k, n)
  const float* W2   = (const float*)d_in[4];  // (H, H) (k, n)
  const float* vt   = (const float*)d_in[5];  // (H,)
  float* out = (float*)d_out;

  // Workspace layout
  float* peT = (float*)d_ws;                            // (H, B*ENC)   6.29 MB
  float* pdm = peT + (size_t)H_SZ * B_SZ * ENC_SZ;      // (B*DEC, H)   1.57 MB
  unsigned short* W1T  = (unsigned short*)(pdm + (size_t)B_SZ * DEC_SZ * H_SZ);
  unsigned short* W2T  = W1T + (size_t)H_SZ * H_SZ;
  unsigned short* encB = W2T + (size_t)H_SZ * H_SZ;     // (B*ENC, H) bf16
  unsigned short* decB = encB + (size_t)B_SZ * ENC_SZ * H_SZ;  // (B*DEC, H) bf16

  transpose_w<<<dim3(12, 12, 2), 256, 0, stream>>>(W1, W2, W1T, W2T);
  cast_bf16<<<dim3(B_SZ * ENC_SZ * H_SZ / 4 / 256, 1, 2), 256, 0, stream>>>(
      enc, dec, encB, decB);

  // peT[h][(b,e)] = exp2(C2 * sum_k W1T[h][k] * encB[(b,e)][k])
  gemm_nt_exp<128><<<dim3(H_SZ / 128, B_SZ * ENC_SZ / 64), 256, 0, stream>>>(
      W1T, encB, peT, B_SZ * ENC_SZ);
  // pdm[(b,d)][h] = exp2(C2 * sum_k decB[(b,d)][k] * W2T[h][k])
  gemm_nt_exp<64><<<dim3(B_SZ * DEC_SZ / 64, H_SZ / 64), 256, 0, stream>>>(
      decB, W2T, pdm, H_SZ);

  // fused score + mask + both outputs
  score_out<<<dim3(ENC_SZ / 64, DEC_SZ / 8, B_SZ), 128, 0, stream>>>(
      peT, pdm, vt, mask, out);
}

// Round 4
// 142.540 us; speedup vs baseline: 1.0846x; 1.0846x over previous
//
#include <hip/hip_runtime.h>
#include <hip/hip_bf16.h>

#define B_SZ   4
#define DEC_SZ 128
#define ENC_SZ 512
#define H_SZ   768
#define OUT_N  (B_SZ * DEC_SZ * ENC_SZ)

typedef __attribute__((ext_vector_type(8))) short s8v;   // 8 bf16 (4 VGPRs)
typedef __attribute__((ext_vector_type(4))) float fvec4; // MFMA accumulator

// fp32 -> bf16, round-to-nearest-even
__device__ inline unsigned short f2bf(float x) {
  union { float f; unsigned u; } v; v.f = x;
  unsigned r = v.u + 0x7FFF + ((v.u >> 16) & 1);
  return (unsigned short)(r >> 16);
}

// ---------------------------------------------------------------------------
// Prep: transpose W (768x768 fp32, (k,n)) -> WT bf16 (n,k). z selects W1/W2.
// ---------------------------------------------------------------------------
__global__ __launch_bounds__(256) void transpose_w(const float* __restrict__ W1,
                                                   const float* __restrict__ W2,
                                                   unsigned short* __restrict__ T1,
                                                   unsigned short* __restrict__ T2) {
  const float* W = blockIdx.z ? W2 : W1;
  unsigned short* T = blockIdx.z ? T2 : T1;
  __shared__ float tile[64][65];
  int c0 = blockIdx.x * 64;
  int r0 = blockIdx.y * 64;
  int tx = threadIdx.x & 63, ty = threadIdx.x >> 6;
#pragma unroll
  for (int i = 0; i < 16; ++i) {
    int r = ty + i * 4;
    tile[r][tx] = W[(size_t)(r0 + r) * H_SZ + c0 + tx];
  }
  __syncthreads();
#pragma unroll
  for (int i = 0; i < 16; ++i) {
    int c = ty + i * 4;
    T[(size_t)(c0 + c) * H_SZ + r0 + tx] = f2bf(tile[tx][c]);
  }
}

// Prep: fp32 -> bf16 for enc (z=0) and dec (z=1)
__global__ __launch_bounds__(256) void cast_bf16(const float* __restrict__ enc,
                                                 const float* __restrict__ dec,
                                                 unsigned short* __restrict__ encB,
                                                 unsigned short* __restrict__ decB) {
  const float* x = blockIdx.z ? dec : enc;
  unsigned short* y = blockIdx.z ? decB : encB;
  int n4 = blockIdx.z ? (B_SZ * DEC_SZ * H_SZ / 4) : (B_SZ * ENC_SZ * H_SZ / 4);
  int i = blockIdx.x * 256 + threadIdx.x;
  if (i >= n4) return;
  float4 v = ((const float4*)x)[i];
  ushort4 o;
  o.x = f2bf(v.x); o.y = f2bf(v.y); o.z = f2bf(v.z); o.w = f2bf(v.w);
  ((ushort4*)y)[i] = o;
}

// ---------------------------------------------------------------------------
// MFMA NT GEMM + exp2 epilogue, register-prefetch double-buffered.
// Computes E[m][n] = exp2(C2 * sum_k A[m][k]*B[n][k]).
// TILED=false: store E[m][n] row-major (ldc = row length).
// TILED=true : m = h (0..767), n = (b*ENC + e); store to pe tile layout
//              float4 index ((b*8 + e/64)*192 + h/4)*64 + (e&63), component h&3.
// ---------------------------------------------------------------------------
template <int TM, bool TILED>
__global__ __launch_bounds__(256) void gemm_nt_exp(const unsigned short* __restrict__ A,
                                                   const unsigned short* __restrict__ Bm,
                                                   float* __restrict__ C, int ldc) {
  const int m0 = blockIdx.x * TM;
  const int n0 = blockIdx.y * 64;

  __shared__ unsigned short As[TM][40];  // pad 40: 80 B rows
  __shared__ unsigned short Bs[64][40];

  const int tid  = threadIdx.x;
  const int wave = tid >> 6;
  const int lane = tid & 63;
  const int l16  = lane & 15;
  const int quad = lane >> 4;
  const int MI   = TM / 64;            // af count (2 for TM=128, 1 for TM=64)
  const int wm   = wave * (TM / 4);

  const int ASEG = TM * 4 / 256;       // per-thread A segments of 8 bf16
  int ar[2], ak[2];
#pragma unroll
  for (int i = 0; i < ASEG; ++i) {
    int seg = tid + 256 * i;
    ar[i] = seg >> 2; ak[i] = (seg & 3) * 8;
  }
  const int br = tid >> 2, bk = (tid & 3) * 8;

  fvec4 acc[2][4];
#pragma unroll
  for (int i = 0; i < 2; ++i)
#pragma unroll
    for (int j = 0; j < 4; ++j) acc[i][j] = (fvec4)0.f;

  s8v pa[2], pb;
#pragma unroll
  for (int i = 0; i < ASEG; ++i)
    pa[i] = *(const s8v*)(A + (size_t)(m0 + ar[i]) * H_SZ + ak[i]);
  pb = *(const s8v*)(Bm + (size_t)(n0 + br) * H_SZ + bk);

  for (int k0 = 0; k0 < H_SZ; k0 += 32) {
    __syncthreads();
#pragma unroll
    for (int i = 0; i < ASEG; ++i) *(s8v*)&As[ar[i]][ak[i]] = pa[i];
    *(s8v*)&Bs[br][bk] = pb;
    __syncthreads();

    if (k0 + 32 < H_SZ) {
#pragma unroll
      for (int i = 0; i < ASEG; ++i)
        pa[i] = *(const s8v*)(A + (size_t)(m0 + ar[i]) * H_SZ + k0 + 32 + ak[i]);
      pb = *(const s8v*)(Bm + (size_t)(n0 + br) * H_SZ + k0 + 32 + bk);
    }

    s8v af[2], bf[4];
#pragma unroll
    for (int i = 0; i < MI; ++i) af[i] = *(const s8v*)&As[wm + i * 16 + l16][quad * 8];
#pragma unroll
    for (int j = 0; j < 4; ++j) bf[j] = *(const s8v*)&Bs[j * 16 + l16][quad * 8];
#pragma unroll
    for (int i = 0; i < MI; ++i)
#pragma unroll
      for (int j = 0; j < 4; ++j)
        acc[i][j] = __builtin_amdgcn_mfma_f32_16x16x32_bf16(af[i], bf[j], acc[i][j], 0, 0, 0);
  }

  const float C2 = 2.885390082f;  // 2 * log2(e)
#pragma unroll
  for (int i = 0; i < MI; ++i) {
    int mbase = m0 + wm + i * 16 + quad * 4;  // C/D: row = quad*4 + reg, col = lane&15
#pragma unroll
    for (int j = 0; j < 4; ++j) {
      int n = n0 + j * 16 + l16;
      if (TILED) {
        float4 o;
        o.x = __builtin_amdgcn_exp2f(acc[i][j][0] * C2);
        o.y = __builtin_amdgcn_exp2f(acc[i][j][1] * C2);
        o.z = __builtin_amdgcn_exp2f(acc[i][j][2] * C2);
        o.w = __builtin_amdgcn_exp2f(acc[i][j][3] * C2);
        int bIdx = n >> 9, es = (n >> 6) & 7, el = n & 63;
        ((float4*)C)[((size_t)(bIdx * 8 + es) * 192 + (mbase >> 2)) * 64 + el] = o;
      } else {
#pragma unroll
        for (int r = 0; r < 4; ++r)
          C[(size_t)(mbase + r) * ldc + n] = __builtin_amdgcn_exp2f(acc[i][j][r] * C2);
      }
    }
  }
}

// ---------------------------------------------------------------------------
// Fused score + mask + outputs.
// out0[b][d][e] = sumv - 2*sum_k vk/(1+pe*pd) + mask;  out1 = same w/o mask.
// Grid (ENC/64, DEC/8, B); block 256 = 4 waves. lane = e within the 64-strip.
// Wave w owns d = d0 + 2w, 2w+1 over full k=768. All 4 waves stream the SAME
// pe column (L1 reuse). pe layout: float4[(b*8+es)*192 + k/4][64] per lane.
// ---------------------------------------------------------------------------
__global__ __launch_bounds__(256) void score_out(const float* __restrict__ peT,
                                                 const float* __restrict__ pdm,
                                                 const float* __restrict__ vt,
                                                 const float* __restrict__ mask,
                                                 float* __restrict__ out) {
  const int tid  = threadIdx.x;
  const int wave = tid >> 6;
  const int lane = tid & 63;
  const int es   = blockIdx.x;
  const int d0   = blockIdx.y * 8;
  const int b    = blockIdx.z;

  __shared__ float pd_s[8][776];   // [d][k], pad 8: rows stay 16B aligned
  __shared__ float vts[768];

  {  // stage pd: thread t -> d = t>>5, l = t&31; 6 float4 per thread
    const int d = tid >> 5, l = tid & 31;
    const float* row = pdm + (size_t)(b * DEC_SZ + d0 + d) * H_SZ;
#pragma unroll
    for (int i = 0; i < 6; ++i)
      *(float4*)&pd_s[d][l * 4 + i * 128] = *(const float4*)(row + l * 4 + i * 128);
  }
  if (tid < 192) *(float4*)&vts[tid * 4] = *(const float4*)(vt + tid * 4);
  __syncthreads();

  // sumv = sum(vt): lane-strided partials + wave butterfly
  float sumv = 0.f;
#pragma unroll
  for (int j = 0; j < 12; ++j) sumv += vts[lane + 64 * j];
#pragma unroll
  for (int s = 1; s < 64; s <<= 1) sumv += __shfl_xor(sumv, s, 64);

  float t0 = 0.f, t1 = 0.f;
  const float4* pe4 = (const float4*)peT + (size_t)(b * 8 + es) * 192 * 64 + lane;

  float4 buf[4];
#pragma unroll
  for (int i = 0; i < 4; ++i) buf[i] = pe4[(size_t)i * 64];

#pragma unroll 4
  for (int c = 0; c < 192; ++c) {
    float4 cur = buf[c & 3];
    if (c + 4 < 192) buf[c & 3] = pe4[(size_t)(c + 4) * 64];
    float4 v4 = *(const float4*)&vts[c * 4];
    float4 p0 = *(const float4*)&pd_s[wave * 2 + 0][c * 4];
    float4 p1 = *(const float4*)&pd_s[wave * 2 + 1][c * 4];
    t0 = fmaf(v4.x, __builtin_amdgcn_rcpf(fmaf(cur.x, p0.x, 1.f)), t0);
    t0 = fmaf(v4.y, __builtin_amdgcn_rcpf(fmaf(cur.y, p0.y, 1.f)), t0);
    t0 = fmaf(v4.z, __builtin_amdgcn_rcpf(fmaf(cur.z, p0.z, 1.f)), t0);
    t0 = fmaf(v4.w, __builtin_amdgcn_rcpf(fmaf(cur.w, p0.w, 1.f)), t0);
    t1 = fmaf(v4.x, __builtin_amdgcn_rcpf(fmaf(cur.x, p1.x, 1.f)), t1);
    t1 = fmaf(v4.y, __builtin_amdgcn_rcpf(fmaf(cur.y, p1.y, 1.f)), t1);
    t1 = fmaf(v4.z, __builtin_amdgcn_rcpf(fmaf(cur.z, p1.z, 1.f)), t1);
    t1 = fmaf(v4.w, __builtin_amdgcn_rcpf(fmaf(cur.w, p1.w, 1.f)), t1);
  }

  const int e = es * 64 + lane;
#pragma unroll
  for (int dd = 0; dd < 2; ++dd) {
    int d = d0 + wave * 2 + dd;
    size_t idx = ((size_t)(b * DEC_SZ + d)) * ENC_SZ + e;
    float s = fmaf(-2.f, dd ? t1 : t0, sumv);
    out[idx] = s + mask[idx];
    out[OUT_N + idx] = s;
  }
}

extern "C" void kernel_launch(void* const* d_in, const int* in_sizes, int n_in,
                              void* d_out, int out_size, void* d_ws, size_t ws_size,
                              hipStream_t stream) {
  (void)in_sizes; (void)n_in; (void)out_size; (void)ws_size;
  const float* dec  = (const float*)d_in[0];  // (B, DEC, H)
  const float* enc  = (const float*)d_in[1];  // (B, ENC, H)
  const float* mask = (const float*)d_in[2];  // (B, DEC, ENC)
  const float* W1   = (const float*)d_in[3];  // (H, H) (k, n)
  const float* W2   = (const float*)d_in[4];  // (H, H) (k, n)
  const float* vt   = (const float*)d_in[5];  // (H,)
  float* out = (float*)d_out;

  // Workspace layout
  float* peT = (float*)d_ws;                            // tiled (B,8,192,64,4) 6.29 MB
  float* pdm = peT + (size_t)H_SZ * B_SZ * ENC_SZ;      // (B*DEC, H)   1.57 MB
  unsigned short* W1T  = (unsigned short*)(pdm + (size_t)B_SZ * DEC_SZ * H_SZ);
  unsigned short* W2T  = W1T + (size_t)H_SZ * H_SZ;
  unsigned short* encB = W2T + (size_t)H_SZ * H_SZ;     // (B*ENC, H) bf16
  unsigned short* decB = encB + (size_t)B_SZ * ENC_SZ * H_SZ;  // (B*DEC, H) bf16

  transpose_w<<<dim3(12, 12, 2), 256, 0, stream>>>(W1, W2, W1T, W2T);
  cast_bf16<<<dim3(B_SZ * ENC_SZ * H_SZ / 4 / 256, 1, 2), 256, 0, stream>>>(
      enc, dec, encB, decB);

  // pe (tiled): exp2(C2 * W1T[h,:] . encB[(b,e),:])
  gemm_nt_exp<128, true><<<dim3(H_SZ / 128, B_SZ * ENC_SZ / 64), 256, 0, stream>>>(
      W1T, encB, peT, 0);
  // pd: pdm[(b,d)][h] = exp2(C2 * decB[(b,d),:] . W2T[h,:])
  gemm_nt_exp<64, false><<<dim3(B_SZ * DEC_SZ / 64, H_SZ / 64), 256, 0, stream>>>(
      decB, W2T, pdm, H_SZ);

  // fused score + mask + both outputs
  score_out<<<dim3(ENC_SZ / 64, DEC_SZ / 8, B_SZ), 256, 0, stream>>>(
      peT, pdm, vt, mask, out);
}

// Round 5
// 133.223 us; speedup vs baseline: 1.1604x; 1.0699x over previous
//
#include <hip/hip_runtime.h>
#include <hip/hip_bf16.h>

#define B_SZ   4
#define DEC_SZ 128
#define ENC_SZ 512
#define H_SZ   768
#define OUT_N  (B_SZ * DEC_SZ * ENC_SZ)

typedef __attribute__((ext_vector_type(8))) short s8v;   // 8 bf16 (4 VGPRs)
typedef __attribute__((ext_vector_type(4))) float fvec4; // MFMA accumulator

// fp32 -> bf16, round-to-nearest-even
__device__ inline unsigned short f2bf(float x) {
  union { float f; unsigned u; } v; v.f = x;
  unsigned r = v.u + 0x7FFF + ((v.u >> 16) & 1);
  return (unsigned short)(r >> 16);
}

// load 8 k-contiguous elements as bf16x8 (converting if fp32 source)
__device__ inline s8v load8(const unsigned short* p) { return *(const s8v*)p; }
__device__ inline s8v load8(const float* p) {
  float4 a = ((const float4*)p)[0];
  float4 b = ((const float4*)p)[1];
  unsigned short r[8] = {f2bf(a.x), f2bf(a.y), f2bf(a.z), f2bf(a.w),
                         f2bf(b.x), f2bf(b.y), f2bf(b.z), f2bf(b.w)};
  return *(const s8v*)r;
}

// ---------------------------------------------------------------------------
// Prep: transpose W (768x768 fp32, (k,n)) -> WT bf16 (n,k). z selects W1/W2.
// ---------------------------------------------------------------------------
__global__ __launch_bounds__(256) void transpose_w(const float* __restrict__ W1,
                                                   const float* __restrict__ W2,
                                                   unsigned short* __restrict__ T1,
                                                   unsigned short* __restrict__ T2) {
  const float* W = blockIdx.z ? W2 : W1;
  unsigned short* T = blockIdx.z ? T2 : T1;
  __shared__ float tile[64][65];
  int c0 = blockIdx.x * 64;
  int r0 = blockIdx.y * 64;
  int tx = threadIdx.x & 63, ty = threadIdx.x >> 6;
#pragma unroll
  for (int i = 0; i < 16; ++i) {
    int r = ty + i * 4;
    tile[r][tx] = W[(size_t)(r0 + r) * H_SZ + c0 + tx];
  }
  __syncthreads();
#pragma unroll
  for (int i = 0; i < 16; ++i) {
    int c = ty + i * 4;
    T[(size_t)(c0 + c) * H_SZ + r0 + tx] = f2bf(tile[tx][c]);
  }
}

// ---------------------------------------------------------------------------
// MFMA NT GEMM body + exp2 epilogue, register-prefetch double-buffered.
// E[m][n] = exp2(C2 * sum_k A[m][k]*B[n][k]); A,B k-contiguous rows (len H).
// Tile 128x64, BK=32, 4 waves; fp32 operands converted to bf16 during staging.
// TILED: m = h, n = (b*ENC+e); float4 store to pe tile layout
//        ((b*8 + e/64)*192 + h/4)*64 + (e&63), component h&3.
// ---------------------------------------------------------------------------
template <bool TILED, typename TA, typename TB>
__device__ inline void gemm_body(const TA* __restrict__ A, const TB* __restrict__ B,
                                 float* __restrict__ C, int ldc, int bx, int by) {
  const int m0 = bx * 128;
  const int n0 = by * 64;

  __shared__ unsigned short As[128][40];  // pad 40: 80 B rows
  __shared__ unsigned short Bs[64][40];

  const int tid  = threadIdx.x;
  const int wave = tid >> 6;
  const int lane = tid & 63;
  const int l16  = lane & 15;
  const int quad = lane >> 4;
  const int wm   = wave * 32;

  int ar[2], ak[2];
#pragma unroll
  for (int i = 0; i < 2; ++i) {
    int seg = tid + 256 * i;
    ar[i] = seg >> 2; ak[i] = (seg & 3) * 8;
  }
  const int br = tid >> 2, bk = (tid & 3) * 8;

  fvec4 acc[2][4];
#pragma unroll
  for (int i = 0; i < 2; ++i)
#pragma unroll
    for (int j = 0; j < 4; ++j) acc[i][j] = (fvec4)0.f;

  s8v pa[2], pb;
#pragma unroll
  for (int i = 0; i < 2; ++i) pa[i] = load8(A + (size_t)(m0 + ar[i]) * H_SZ + ak[i]);
  pb = load8(B + (size_t)(n0 + br) * H_SZ + bk);

  for (int k0 = 0; k0 < H_SZ; k0 += 32) {
    __syncthreads();
#pragma unroll
    for (int i = 0; i < 2; ++i) *(s8v*)&As[ar[i]][ak[i]] = pa[i];
    *(s8v*)&Bs[br][bk] = pb;
    __syncthreads();

    if (k0 + 32 < H_SZ) {
#pragma unroll
      for (int i = 0; i < 2; ++i)
        pa[i] = load8(A + (size_t)(m0 + ar[i]) * H_SZ + k0 + 32 + ak[i]);
      pb = load8(B + (size_t)(n0 + br) * H_SZ + k0 + 32 + bk);
    }

    s8v af[2], bf[4];
#pragma unroll
    for (int i = 0; i < 2; ++i) af[i] = *(const s8v*)&As[wm + i * 16 + l16][quad * 8];
#pragma unroll
    for (int j = 0; j < 4; ++j) bf[j] = *(const s8v*)&Bs[j * 16 + l16][quad * 8];
#pragma unroll
    for (int i = 0; i < 2; ++i)
#pragma unroll
      for (int j = 0; j < 4; ++j)
        acc[i][j] = __builtin_amdgcn_mfma_f32_16x16x32_bf16(af[i], bf[j], acc[i][j], 0, 0, 0);
  }

  const float C2 = 2.885390082f;  // 2 * log2(e)
#pragma unroll
  for (int i = 0; i < 2; ++i) {
    int mbase = m0 + wm + i * 16 + quad * 4;  // C/D: row = quad*4 + reg, col = l16
#pragma unroll
    for (int j = 0; j < 4; ++j) {
      int n = n0 + j * 16 + l16;
      if (TILED) {
        float4 o;
        o.x = __builtin_amdgcn_exp2f(acc[i][j][0] * C2);
        o.y = __builtin_amdgcn_exp2f(acc[i][j][1] * C2);
        o.z = __builtin_amdgcn_exp2f(acc[i][j][2] * C2);
        o.w = __builtin_amdgcn_exp2f(acc[i][j][3] * C2);
        int bIdx = n >> 9, es = (n >> 6) & 7, el = n & 63;
        ((float4*)C)[((size_t)(bIdx * 8 + es) * 192 + (mbase >> 2)) * 64 + el] = o;
      } else {
#pragma unroll
        for (int r = 0; r < 4; ++r)
          C[(size_t)(mbase + r) * ldc + n] = __builtin_amdgcn_exp2f(acc[i][j][r] * C2);
      }
    }
  }
}

// Both GEMMs in one launch: blocks 0..191 -> pe GEMM, 192..239 -> pd GEMM.
__global__ __launch_bounds__(256) void gemm_both(const unsigned short* __restrict__ W1T,
                                                 const float* __restrict__ enc,
                                                 const float* __restrict__ dec,
                                                 const unsigned short* __restrict__ W2T,
                                                 float* __restrict__ peT,
                                                 float* __restrict__ pdm) {
  int bid = blockIdx.x;
  if (bid < 192) {
    // peT tiled: m=h (768 -> 6 tiles), n=(b,e) (2048 -> 32 tiles)
    gemm_body<true>(W1T, enc, peT, 0, bid % 6, bid / 6);
  } else {
    // pdm[(b,d)][h]: m=(b,d) (512 -> 4 tiles), n=h (768 -> 12 tiles)
    int r = bid - 192;
    gemm_body<false>(dec, W2T, pdm, H_SZ, r % 4, r / 4);
  }
}

// ---------------------------------------------------------------------------
// Fused score + mask + outputs — NO LDS, scalar (SGPR) loads for vt/pd.
// out0[b][d][e] = sumv - 2*sum_k vk/(1+pe*pd) + mask;  out1 = same w/o mask.
// Grid (ENC/64, DEC/4, B); block 256 = 4 waves; wave w owns d = d0 + w.
// pe layout: float4[(b*8+es)*192 + k/4][64lane].
// ---------------------------------------------------------------------------
__global__ __launch_bounds__(256) void score_out(const float* __restrict__ peT,
                                                 const float* __restrict__ pdm,
                                                 const float* __restrict__ vt,
                                                 const float* __restrict__ mask,
                                                 float* __restrict__ out) {
  const int tid  = threadIdx.x;
  const int lane = tid & 63;
  // force wave id into SGPR so pd-row address is provably wave-uniform
  const int wave = __builtin_amdgcn_readfirstlane(tid >> 6);
  const int es   = blockIdx.x;
  const int b    = blockIdx.z;
  const int d    = blockIdx.y * 4 + wave;

  // sumv = sum(vt): lane-strided global loads + butterfly
  float sumv = 0.f;
#pragma unroll
  for (int j = 0; j < 12; ++j) sumv += vt[lane + 64 * j];
#pragma unroll
  for (int s = 1; s < 64; s <<= 1) sumv += __shfl_xor(sumv, s, 64);

  const float* pdrow = pdm + (size_t)(b * DEC_SZ + d) * H_SZ;  // wave-uniform
  const float4* pe4 = (const float4*)peT + (size_t)(b * 8 + es) * 192 * 64 + lane;

  float t0 = 0.f;
  float4 buf[8];
#pragma unroll
  for (int i = 0; i < 8; ++i) buf[i] = pe4[(size_t)i * 64];

#pragma unroll 8
  for (int c = 0; c < 192; ++c) {
    float4 cur = buf[c & 7];
    if (c + 8 < 192) buf[c & 7] = pe4[(size_t)(c + 8) * 64];
    float4 v4 = *(const float4*)(vt + c * 4);      // uniform -> s_load
    float4 p4 = *(const float4*)(pdrow + c * 4);   // uniform -> s_load
    t0 = fmaf(v4.x, __builtin_amdgcn_rcpf(fmaf(cur.x, p4.x, 1.f)), t0);
    t0 = fmaf(v4.y, __builtin_amdgcn_rcpf(fmaf(cur.y, p4.y, 1.f)), t0);
    t0 = fmaf(v4.z, __builtin_amdgcn_rcpf(fmaf(cur.z, p4.z, 1.f)), t0);
    t0 = fmaf(v4.w, __builtin_amdgcn_rcpf(fmaf(cur.w, p4.w, 1.f)), t0);
  }

  const int e = es * 64 + lane;
  size_t idx = ((size_t)(b * DEC_SZ + d)) * ENC_SZ + e;
  float s = fmaf(-2.f, t0, sumv);
  out[idx] = s + mask[idx];
  out[OUT_N + idx] = s;
}

extern "C" void kernel_launch(void* const* d_in, const int* in_sizes, int n_in,
                              void* d_out, int out_size, void* d_ws, size_t ws_size,
                              hipStream_t stream) {
  (void)in_sizes; (void)n_in; (void)out_size; (void)ws_size;
  const float* dec  = (const float*)d_in[0];  // (B, DEC, H)
  const float* enc  = (const float*)d_in[1];  // (B, ENC, H)
  const float* mask = (const float*)d_in[2];  // (B, DEC, ENC)
  const float* W1   = (const float*)d_in[3];  // (H, H) (k, n)
  const float* W2   = (const float*)d_in[4];  // (H, H) (k, n)
  const float* vt   = (const float*)d_in[5];  // (H,)
  float* out = (float*)d_out;

  // Workspace layout
  float* peT = (float*)d_ws;                            // tiled (B,8,192,64,4) 6.29 MB
  float* pdm = peT + (size_t)H_SZ * B_SZ * ENC_SZ;      // (B*DEC, H)   1.57 MB
  unsigned short* W1T = (unsigned short*)(pdm + (size_t)B_SZ * DEC_SZ * H_SZ);
  unsigned short* W2T = W1T + (size_t)H_SZ * H_SZ;

  transpose_w<<<dim3(12, 12, 2), 256, 0, stream>>>(W1, W2, W1T, W2T);
  gemm_both<<<dim3(240), 256, 0, stream>>>(W1T, enc, dec, W2T, peT, pdm);
  score_out<<<dim3(ENC_SZ / 64, DEC_SZ / 4, B_SZ), 256, 0, stream>>>(
      peT, pdm, vt, mask, out);
}